// Round 1
// baseline (450.223 us; speedup 1.0000x reference)
//
#include <hip/hip_runtime.h>

// LocallyConnected2d: out[b,o,h,w] = sum_{c,k} x[b,c,h+kh-1,w+kw-1] * wgt[o,c,h,w,k]
// B=8 C=32 O=64 H=W=64 K=9 (kh-major). fp32 in / fp32 out.
//
// Memory-bound on the 302 MB fp32 weight stream (read exactly once); roofline ~48us.
// R2 theory: the old per-thread scalar weight loads (9 dwords at lane-stride 36B)
// were address-divergence bound in the VMEM/TA pipe (~36 lines touched per wave
// instruction, L1 thrash on the k re-reads) -> 0.75 TB/s effective. Fix: stage the
// contiguous 576-dword (o,c,h) weight slab through LDS with fully-coalesced,
// 16B-aligned float4 loads (contiguous 512B runs per half-wave), then read the
// per-thread k-vector from LDS (dword stride 9; 9 coprime 32 banks -> 2 lanes/bank,
// free). x tile staging unchanged (already contiguous dword loads).
//
// - thread = (w=lane, o-pair), holds all 8 batch accumulators -> weight used 8x/read
// - LDS: x tile 12.7 KB + weight slab 2x18 KB = 49.5 KB/block, 2 blocks/CU
// - 512 blocks (h x o-octet) x 256 thr; both LDS buffers double-buffered,
//   next-c global loads prefetched into registers; 1 barrier per c-iter.

#define BB 8
#define CC 32
#define OO 64
#define HH 64
#define WW 64
#define KK 9
#define CHW (CC * HH * WW)      // x batch stride  (131072)
#define OHW (HH * WW)           // x channel stride (4096)
#define WCS (HH * WW * KK)      // wgt channel stride in floats (36864)
#define WOS (CC * HH * WW * KK) // wgt o stride in floats (1179648)
#define WROW (WW * KK)          // wgt dwords per (o,c,h) slab (576)

__global__ __launch_bounds__(256, 2)
void lc2d_kernel(const float* __restrict__ x,
                 const float* __restrict__ wgt,
                 float* __restrict__ out)
{
  const int tid  = threadIdx.x;
  const int w    = tid & 63;
  const int osub = tid >> 6;          // 0..3 (wave id)
  const int h    = blockIdx.x & 63;
  const int og   = blockIdx.x >> 6;   // 0..7
  const int o0   = og * 8 + osub * 2; // this thread: o0, o0+1

  // LDS x tile for one c: [buf][half(b0-3|b4-7)][ (dh*66 + w') ], float4 per entry.
  __shared__ float4 xs[2][2][198];
  // LDS weight slab for one c: [buf][o'*576 + w*9 + k], linear global order per o.
  __shared__ float wsh[2][8 * WROW];

  // ---- x staging coords (threads 0..197 stage one (dh,w') position, all 8 b) ----
  const int p   = tid;
  const int dh  = (p >= 132) ? 2 : ((p >= 66) ? 1 : 0);
  const int wpp = p - dh * 66;
  const int r   = h + dh - 1;
  const int col = wpp - 1;
  const bool sactive = (p < 198);
  const bool svalid  = sactive && (r >= 0) && (r < HH) && (col >= 0) && (col < WW);
  const int xoff0 = r * WW + col;     // + c*OHW + b*CHW

  // ---- weight staging coords: 32 threads per o-chunk, 144 float4 per chunk ----
  const int soi = tid >> 5;           // 0..7 : which o of the octet this thread stages
  const int sl  = tid & 31;           // 0..31: float4 lane within the chunk
  const float* wchunk = wgt + (og * 8 + soi) * WOS + h * WROW;  // + c*WCS

  float acc[2][8];
#pragma unroll
  for (int j = 0; j < 2; ++j)
#pragma unroll
    for (int b = 0; b < 8; ++b) acc[j][b] = 0.f;

  auto load_stage = [&](int c, float4& lo, float4& hi) {
    lo = make_float4(0.f, 0.f, 0.f, 0.f);
    hi = make_float4(0.f, 0.f, 0.f, 0.f);
    if (svalid) {
      const float* q = x + (xoff0 + c * OHW);
      lo.x = q[0 * CHW]; lo.y = q[1 * CHW]; lo.z = q[2 * CHW]; lo.w = q[3 * CHW];
      hi.x = q[4 * CHW]; hi.y = q[5 * CHW]; hi.z = q[6 * CHW]; hi.w = q[7 * CHW];
    }
  };

  // coalesced: 32 consecutive lanes read 512B contiguous runs, 16B-aligned
  auto load_wstage = [&](int c, float4 (&wv)[5]) {
    const float4* src = reinterpret_cast<const float4*>(wchunk + c * WCS);
#pragma unroll
    for (int jj = 0; jj < 4; ++jj) wv[jj] = src[sl + 32 * jj];
    if (sl < 16) wv[4] = src[sl + 128];     // 144 float4 per chunk = 4.5*32
  };

  auto store_wstage = [&](int buf, const float4 (&wv)[5]) {
    float4* dst = reinterpret_cast<float4*>(&wsh[buf][0]) + soi * 144;
#pragma unroll
    for (int jj = 0; jj < 4; ++jj) dst[sl + 32 * jj] = wv[jj];
    if (sl < 16) dst[sl + 128] = wv[4];
  };

  auto compute = [&](int cur) {
    // weights for this thread's two o's: dword index (osub*2+j)*576 + w*9 + k.
    // lane-bank pattern w*9 mod 32: 9 coprime 32 -> exactly 2 lanes/bank (free).
    const float* wp = &wsh[cur][(osub * 2) * WROW + w * KK];
    float wrr[2][KK];
#pragma unroll
    for (int k = 0; k < KK; ++k) {
      wrr[0][k] = wp[k];
      wrr[1][k] = wp[WROW + k];
    }
    float4 plo[KK], phi[KK];
#pragma unroll
    for (int d = 0; d < 3; ++d)
#pragma unroll
      for (int e = 0; e < 3; ++e) {
        plo[d * 3 + e] = xs[cur][0][d * 66 + w + e];
        phi[d * 3 + e] = xs[cur][1][d * 66 + w + e];
      }
#pragma unroll
    for (int k = 0; k < KK; ++k) {
      float xf[8];
      xf[0] = plo[k].x; xf[1] = plo[k].y; xf[2] = plo[k].z; xf[3] = plo[k].w;
      xf[4] = phi[k].x; xf[5] = phi[k].y; xf[6] = phi[k].z; xf[7] = phi[k].w;
#pragma unroll
      for (int j = 0; j < 2; ++j) {
        const float wf = wrr[j][k];
#pragma unroll
        for (int b = 0; b < 8; ++b)
          acc[j][b] = fmaf(wf, xf[b], acc[j][b]);
      }
    }
  };

  // ---- prologue: stage c=0 (x and weights) ----
  float4 slo, shi;
  float4 wv[5];
  load_stage(0, slo, shi);
  load_wstage(0, wv);
  if (sactive) { xs[0][0][p] = slo; xs[0][1][p] = shi; }
  store_wstage(0, wv);
  __syncthreads();

  // ---- main loop: prefetch c+1 into regs, compute c, store c+1, one barrier ----
  for (int c = 0; c < CC - 1; ++c) {
    float4 nlo, nhi;
    float4 nwv[5];
    load_stage(c + 1, nlo, nhi);
    load_wstage(c + 1, nwv);

    compute(c & 1);

    if (sactive) { xs[(c + 1) & 1][0][p] = nlo; xs[(c + 1) & 1][1][p] = nhi; }
    store_wstage((c + 1) & 1, nwv);
    __syncthreads();
  }
  compute((CC - 1) & 1);

  // ---- epilogue: out[b,o,h,w], lane-consecutive in w -> coalesced ----
#pragma unroll
  for (int j = 0; j < 2; ++j) {
    const int o = o0 + j;
#pragma unroll
    for (int b = 0; b < 8; ++b)
      out[((b * OO + o) * HH + h) * WW + w] = acc[j][b];
  }
}

extern "C" void kernel_launch(void* const* d_in, const int* in_sizes, int n_in,
                              void* d_out, int out_size, void* d_ws, size_t ws_size,
                              hipStream_t stream) {
  const float* x   = (const float*)d_in[0];
  const float* wgt = (const float*)d_in[1];
  float* out       = (float*)d_out;
  (void)in_sizes; (void)n_in; (void)out_size; (void)d_ws; (void)ws_size;
  lc2d_kernel<<<dim3(HH * (OO / 8)), dim3(256), 0, stream>>>(x, wgt, out);
}

// Round 2
// 405.187 us; speedup vs baseline: 1.1111x; 1.1111x over previous
//
#include <hip/hip_runtime.h>

// LocallyConnected2d: out[b,o,h,w] = sum_{c,k} x[b,c,h+kh-1,w+kw-1] * wgt[o,c,h,w,k]
// B=8 C=32 O=64 H=W=64 K=9 (kh-major). fp32 in / fp32 out (per reference; the R1
// NaN proved the buffers are fp32 — bf16 reinterpretation produced NaN patterns).
//
// Memory-bound on the 302 MB fp32 weight stream (read exactly once).
// ROOFLINE NOTE (R2 post-mortem): the harness-timed region contains two ~182 µs
// poison-fill dispatches (1.18 GB writes @6.6 TB/s each); the lc2d dispatch itself
// is ~42-48 µs ≈ 302 MB / 6.3-6.6 TB/s = the achievable HBM floor. Evidence: the
// rocprof top-5 (sorted by dur_us) contains only fill kernels at ~183 µs in every
// round, bounding lc2d < 181 µs; dur_us − 2×fill ≈ 42-48 µs. An LDS-staged weight
// variant (R1) regressed dur_us 405.7→450.2 (kernel ~48→~92 µs: extra LDS
// round-trip + vmcnt(0)-coupled staging pipeline). This version is the roofline.
//
// - thread = (w=lane, o-pair), holds all 8 batch accumulators -> weight read 1x, used 8x
// - x staged per-c into LDS as two stride-16 float4 planes (batches 0-3 / 4-7):
//   ds_read_b128 in the lane-contiguous conflict-free pattern, 2 reads per (dh,dw)
//   position serve 16 FMAs
// - weight loads: 9 consecutive dwords/lane (wave covers a contiguous 2304 B run);
//   L1-resident re-walk, straight to registers, no LDS round-trip
// - 512 blocks (h x o-octet) x 256 thr = 2 blocks/CU, 8 waves/CU; LDS double-buffered,
//   next-c weights + stage prefetched into registers; 1 barrier per c-iter.

#define BB 8
#define CC 32
#define OO 64
#define HH 64
#define WW 64
#define KK 9
#define CHW (CC * HH * WW)   // x batch stride  (131072)
#define OHW (HH * WW)        // x channel stride (4096)
#define WCS (HH * WW * KK)   // wgt channel stride (36864)
#define WOS (CC * HH * WW * KK) // wgt o stride (1179648)

__global__ __launch_bounds__(256, 2)
void lc2d_kernel(const float* __restrict__ x,
                 const float* __restrict__ wgt,
                 float* __restrict__ out)
{
  const int tid  = threadIdx.x;
  const int w    = tid & 63;
  const int osub = tid >> 6;          // 0..3
  const int h    = blockIdx.x & 63;
  const int og   = blockIdx.x >> 6;   // 0..7
  const int o0   = og * 8 + osub * 2; // this thread: o0, o0+1

  // LDS x tile for one c: [buf][half(b0-3|b4-7)][ (dh*66 + w') ], float4 per entry.
  // Stride-16 lane-contiguous reads -> conflict-free ds_read_b128.
  __shared__ float4 xs[2][2][198];

  // ---- staging coords (threads 0..197 stage one (dh,w') position, all 8 b) ----
  const int p   = tid;
  const int dh  = (p >= 132) ? 2 : ((p >= 66) ? 1 : 0);
  const int wpp = p - dh * 66;
  const int r   = h + dh - 1;
  const int col = wpp - 1;
  const bool sactive = (p < 198);
  const bool svalid  = sactive && (r >= 0) && (r < HH) && (col >= 0) && (col < WW);
  const int xoff0 = r * WW + col;     // + c*OHW + b*CHW

  // ---- weight pointers: elem = (((o*CC + c)*HH + h)*WW + w)*KK + k ----
  const float* wq0 = wgt + (o0 * CC * HH + h) * (WW * KK) + w * KK;
  const float* wq1 = wq0 + WOS;       // o0+1

  float acc[2][8];
#pragma unroll
  for (int j = 0; j < 2; ++j)
#pragma unroll
    for (int b = 0; b < 8; ++b) acc[j][b] = 0.f;

  auto load_stage = [&](int c, float4& lo, float4& hi) {
    lo = make_float4(0.f, 0.f, 0.f, 0.f);
    hi = make_float4(0.f, 0.f, 0.f, 0.f);
    if (svalid) {
      const float* q = x + (xoff0 + c * OHW);
      lo.x = q[0 * CHW]; lo.y = q[1 * CHW]; lo.z = q[2 * CHW]; lo.w = q[3 * CHW];
      hi.x = q[4 * CHW]; hi.y = q[5 * CHW]; hi.z = q[6 * CHW]; hi.w = q[7 * CHW];
    }
  };

  auto load_w = [&](int c, float (&wrr)[2][KK]) {
    const float* a = wq0 + c * WCS;
    const float* b = wq1 + c * WCS;
#pragma unroll
    for (int k = 0; k < KK; ++k) { wrr[0][k] = a[k]; wrr[1][k] = b[k]; }
  };

  auto compute = [&](int cur, const float (&wrr)[2][KK]) {
    float4 plo[KK], phi[KK];
#pragma unroll
    for (int d = 0; d < 3; ++d)
#pragma unroll
      for (int e = 0; e < 3; ++e) {
        plo[d * 3 + e] = xs[cur][0][d * 66 + w + e];
        phi[d * 3 + e] = xs[cur][1][d * 66 + w + e];
      }
#pragma unroll
    for (int k = 0; k < KK; ++k) {
      float xf[8];
      xf[0] = plo[k].x; xf[1] = plo[k].y; xf[2] = plo[k].z; xf[3] = plo[k].w;
      xf[4] = phi[k].x; xf[5] = phi[k].y; xf[6] = phi[k].z; xf[7] = phi[k].w;
#pragma unroll
      for (int j = 0; j < 2; ++j) {
        const float wf = wrr[j][k];
#pragma unroll
        for (int b = 0; b < 8; ++b)
          acc[j][b] = fmaf(wf, xf[b], acc[j][b]);
      }
    }
  };

  // ---- prologue: stage c=0, prefetch weights c=0 ----
  float4 slo, shi;
  load_stage(0, slo, shi);
  float wr[2][KK];
  load_w(0, wr);
  if (sactive) { xs[0][0][p] = slo; xs[0][1][p] = shi; }
  __syncthreads();

  // ---- main loop: compute c, prefetch+stage c+1, one barrier per iter ----
  for (int c = 0; c < CC - 1; ++c) {
    float4 nlo, nhi;
    load_stage(c + 1, nlo, nhi);
    float wn[2][KK];
    load_w(c + 1, wn);

    compute(c & 1, wr);

    if (sactive) { xs[(c + 1) & 1][0][p] = nlo; xs[(c + 1) & 1][1][p] = nhi; }
#pragma unroll
    for (int k = 0; k < KK; ++k) { wr[0][k] = wn[0][k]; wr[1][k] = wn[1][k]; }
    __syncthreads();
  }
  compute((CC - 1) & 1, wr);

  // ---- epilogue: out[b,o,h,w], lane-consecutive in w -> coalesced ----
#pragma unroll
  for (int j = 0; j < 2; ++j) {
    const int o = o0 + j;
#pragma unroll
    for (int b = 0; b < 8; ++b)
      out[((b * OO + o) * HH + h) * WW + w] = acc[j][b];
  }
}

extern "C" void kernel_launch(void* const* d_in, const int* in_sizes, int n_in,
                              void* d_out, int out_size, void* d_ws, size_t ws_size,
                              hipStream_t stream) {
  const float* x   = (const float*)d_in[0];
  const float* wgt = (const float*)d_in[1];
  float* out       = (float*)d_out;
  (void)in_sizes; (void)n_in; (void)out_size; (void)d_ws; (void)ws_size;
  lc2d_kernel<<<dim3(HH * (OO / 8)), dim3(256), 0, stream>>>(x, wgt, out);
}